// Round 3
// baseline (400.375 us; speedup 1.0000x reference)
//
#include <hip/hip_runtime.h>

// LocallyConnectedLayer MI355X — R3: latency-tolerant restructure.
// 900 blocks (450 (i,j-pair) tiles x 2 batch-halves), M=64, N=64, K=576 (c-chunk 8).
// A (x-patches): global->register per-lane gather, no LDS.  B (weight): elem-coalesced
// loads -> bf16 packed Bt in LDS (kw'=3 slots pre-zeroed once).  Chunk-local register
// arrays only (no cross-barrier prefetch arrays -> no scratch risk).
// out[b,o,i,j] = bias[o,i,j] + sum_{c,kh,kw} x[b,c,i+kh,j+kw] * W[c,o,i,j,kh,kw]

#define BDIM 256

typedef __bf16 bf16x8 __attribute__((ext_vector_type(8)));
typedef float f32x4 __attribute__((ext_vector_type(4)));

__device__ __forceinline__ unsigned short f2bf(float f) {
  union { float f; unsigned u; } v; v.f = f;
  unsigned r = v.u + 0x7fffu + ((v.u >> 16) & 1u);  // RTNE
  return (unsigned short)(r >> 16);
}

// x:    [128,64,32,32]  strides b:65536 c:1024 h:32 w:1
// wgt:  [64(c),64(o),30,30,3,3] strides c:518400 o:8100 ij:9 kh:3 kw:1
// bias: [64,30,30]; out: [128,64,30,30] strides b:57600 o:900 ij:1

__global__ __launch_bounds__(256, 4) void lcl_kernel(
    const float* __restrict__ x, const float* __restrict__ wgt,
    const float* __restrict__ bias, float* __restrict__ out) {
  // XCD-contiguous mapping over u in [0,900): same tile's 2 b-halves adjacent,
  // adjacent j-tiles on same XCD (weight/x L2 locality).
  int blk = blockIdx.x;
  int xcd = blk & 7, sg = blk >> 3;
  int u = xcd * 112 + (xcd < 4 ? xcd : 4) + sg;  // sizes 113,113,113,113,112,112,112,112
  int tile = u >> 1, bh = u & 1;
  int i = tile / 15, j0 = (tile % 15) * 2;       // j0 even
  int ij0 = i * 30 + j0;                         // even

  // Bt: [dj:2][o:64][k'':96 + 8 pad] bf16; kw'==3 slots stay zero forever.
  __shared__ __align__(16) unsigned short Bt[2 * 64 * 104];   // 26624 B

  const int tid  = threadIdx.x;
  const int wave = tid >> 6;
  const int lane = tid & 63;
  const int lrow = lane & 15;
  const int q    = lane >> 4;
  const int brow = bh * 64 + wave * 16 + lrow;   // this lane's A row (batch index)

  // zero Bt once (chunk staging never writes kw'=3 slots)
  for (int z = tid; z < 3328; z += BDIM) ((unsigned long long*)Bt)[z] = 0ull;

  f32x4 acc[2][4];   // [jj][nt]
#pragma unroll
  for (int a = 0; a < 2; ++a)
#pragma unroll
    for (int c = 0; c < 4; ++c) acc[a][c] = f32x4{0.f, 0.f, 0.f, 0.f};

  const float* wb = wgt + ij0 * 9;                       // + (c0+cc)*518400 + o*8100 + el*2
  const float* xb = x + brow * 65536 + i * 32 + j0;      // + (c0+cc)*1024 + kh*32

  __syncthreads();   // Bt zero visible before first staging writes

  for (int chunk = 0; chunk < 8; ++chunk) {
    const int c0 = chunk * 8;

    // ---- issue B loads: elem-coalesced, 9 consecutive lanes per 18-float run
    float2 wv[18];
#pragma unroll
    for (int p = 0; p < 18; ++p) {
      int e = tid + p * 256;
      int run = e / 9, el = e - run * 9;
      int cc = run >> 6, o = run & 63;
      wv[p] = *(const float2*)(wb + (c0 + cc) * 518400 + o * 8100 + el * 2);
    }
    // ---- issue A loads: per-lane 16-B run for this lane's fragments (2 g per s)
    float2 ax[3][2][2];   // [s][gi][half]
#pragma unroll
    for (int s = 0; s < 3; ++s)
#pragma unroll
      for (int gi = 0; gi < 2; ++gi) {
        int g = s * 8 + q * 2 + gi;
        int cc = g / 3, kh = g - cc * 3;
        const float2* xp = (const float2*)(xb + (c0 + cc) * 1024 + kh * 32);
        ax[s][gi][0] = xp[0];
        ax[s][gi][1] = xp[1];
      }

    if (chunk) __syncthreads();   // previous chunk's MFMA readers done

    // ---- convert + write Bt (slots kw'=0..2 only)
#pragma unroll
    for (int p = 0; p < 18; ++p) {
      int e = tid + p * 256;
      int run = e / 9, el = e - run * 9;
      int cc = run >> 6, o = run & 63;
      int obase = o * 104 + cc * 12;
#pragma unroll
      for (int h = 0; h < 2; ++h) {
        int f = el * 2 + h;            // 0..17
        int jj = f / 9, r9 = f - jj * 9;
        int kh = r9 / 3, kw = r9 - kh * 3;
        Bt[jj * 6656 + obase + kh * 4 + kw] = f2bf(h ? wv[p].y : wv[p].x);
      }
    }
    __syncthreads();

    // ---- MFMA: 3 k-steps, A-frags straight from registers
#pragma unroll
    for (int s = 0; s < 3; ++s) {
      bf16x8 bfr[2][4];
#pragma unroll
      for (int jj = 0; jj < 2; ++jj)
#pragma unroll
        for (int nt = 0; nt < 4; ++nt)
          bfr[jj][nt] = *reinterpret_cast<const bf16x8*>(
              &Bt[jj * 6656 + (nt * 16 + lrow) * 104 + s * 32 + q * 8]);

      unsigned short ha[2][4];
#pragma unroll
      for (int gi = 0; gi < 2; ++gi) {
        ha[gi][0] = f2bf(ax[s][gi][0].x);
        ha[gi][1] = f2bf(ax[s][gi][0].y);
        ha[gi][2] = f2bf(ax[s][gi][1].x);
        ha[gi][3] = f2bf(ax[s][gi][1].y);
      }
      union { unsigned short u[8]; bf16x8 v; } fa0, fa1;
#pragma unroll
      for (int gi = 0; gi < 2; ++gi) {
        fa0.u[gi * 4 + 0] = ha[gi][0];
        fa0.u[gi * 4 + 1] = ha[gi][1];
        fa0.u[gi * 4 + 2] = ha[gi][2];
        fa0.u[gi * 4 + 3] = ha[gi][3];        // slot3 pairs with B zero
        fa1.u[gi * 4 + 0] = ha[gi][1];
        fa1.u[gi * 4 + 1] = ha[gi][2];
        fa1.u[gi * 4 + 2] = ha[gi][3];
        fa1.u[gi * 4 + 3] = ha[gi][0];        // slot3 pairs with B zero
      }
#pragma unroll
      for (int nt = 0; nt < 4; ++nt) {
        acc[0][nt] = __builtin_amdgcn_mfma_f32_16x16x32_bf16(fa0.v, bfr[0][nt], acc[0][nt], 0, 0, 0);
        acc[1][nt] = __builtin_amdgcn_mfma_f32_16x16x32_bf16(fa1.v, bfr[1][nt], acc[1][nt], 0, 0, 0);
      }
    }
  }

  // ---- epilogue: D[row=q*4+r][col=lrow]; row->b(local 16), col->o; float2 over (ij0,ij0+1)
#pragma unroll
  for (int nt = 0; nt < 4; ++nt) {
    int o = nt * 16 + lrow;
    float2 bv = *(const float2*)(bias + o * 900 + ij0);
#pragma unroll
    for (int r = 0; r < 4; ++r) {
      int b = bh * 64 + wave * 16 + q * 4 + r;
      float2 res;
      res.x = acc[0][nt][r] + bv.x;
      res.y = acc[1][nt][r] + bv.y;
      *(float2*)(out + b * 57600 + o * 900 + ij0) = res;
    }
  }
}

extern "C" void kernel_launch(void* const* d_in, const int* in_sizes, int n_in,
                              void* d_out, int out_size, void* d_ws, size_t ws_size,
                              hipStream_t stream) {
  const float* x    = (const float*)d_in[0];
  const float* wgt  = (const float*)d_in[1];
  const float* bias = (const float*)d_in[2];
  float* out        = (float*)d_out;
  lcl_kernel<<<dim3(900), dim3(256), 0, stream>>>(x, wgt, bias, out);
}

// Round 4
// 362.882 us; speedup vs baseline: 1.1033x; 1.1033x over previous
//
#include <hip/hip_runtime.h>

// LocallyConnectedLayer MI355X — R4: O-split (not M-split).
// 900 blocks = 450 (i, j-pair) tiles x 2 o-halves. Per block: M=128, N=32, K=576
// (c-chunks of 8). Weight read exactly once device-wide (disjoint o-halves).
// A (x) gathered straight into registers (fragment layout == memory layout),
// B (weight) element-coalesced into 13.3 KB LDS. Chunk-local register arrays only.
// out[b,o,i,j] = bias[o,i,j] + sum_{c,kh,kw} x[b,c,i+kh,j+kw] * W[c,o,i,j,kh,kw]

#define BDIM 256

typedef __bf16 bf16x8 __attribute__((ext_vector_type(8)));
typedef float f32x4 __attribute__((ext_vector_type(4)));

__device__ __forceinline__ unsigned short f2bf(float f) {
  __bf16 h = (__bf16)f;                      // native v_cvt RTNE on gfx950
  return __builtin_bit_cast(unsigned short, h);
}

// x:    [128,64,32,32]  strides b:65536 c:1024 h:32 w:1
// wgt:  [64(c),64(o),30,30,3,3] strides c:518400 o:8100 ij:9 kh:3 kw:1
// bias: [64,30,30]; out: [128,64,30,30] strides b:57600 o:900 ij:1

__global__ __launch_bounds__(256, 3) void lcl_kernel(
    const float* __restrict__ x, const float* __restrict__ wgt,
    const float* __restrict__ bias, float* __restrict__ out) {
  // XCD-contiguous mapping over u in [0,900): both o-halves of a tile adjacent
  // (share x in L2), adjacent j-tiles on same XCD (weight/x line reuse).
  int blk = blockIdx.x;
  int xcd = blk & 7, sg = blk >> 3;
  int u = xcd * 112 + (xcd < 4 ? xcd : 4) + sg;  // sizes 113,113,113,113,112,112,112,112
  int tile = u >> 1, oh = u & 1;
  int i = tile / 15, j0 = (tile % 15) * 2;       // j0 even
  int ij0 = i * 30 + j0;

  // Bt: [dj:2][o:32][k'':96 + 8 pad] bf16; kw'==3 slots stay zero forever.
  __shared__ __align__(16) unsigned short Bt[2 * 32 * 104];   // 13312 B

  const int tid  = threadIdx.x;
  const int wave = tid >> 6;
  const int lane = tid & 63;
  const int lrow = lane & 15;
  const int q    = lane >> 4;

  // zero Bt once (staging never writes kw'=3 / pad slots)
  for (int z = tid; z < 1664; z += BDIM) ((unsigned long long*)Bt)[z] = 0ull;

  f32x4 acc[2][2][2];   // [mt][jj][nt]
#pragma unroll
  for (int a = 0; a < 2; ++a)
#pragma unroll
    for (int b = 0; b < 2; ++b)
#pragma unroll
      for (int c = 0; c < 2; ++c) acc[a][b][c] = f32x4{0.f, 0.f, 0.f, 0.f};

  const float* wb  = wgt + oh * 32 * 8100 + ij0 * 9;          // + cc_g*518400 + o*8100 + el*2
  const float* xb0 = x + (wave * 32 + lrow) * 65536 + i * 32 + j0;  // mt=0 row
  const float* xb1 = xb0 + 16 * 65536;                               // mt=1 row

  __syncthreads();   // Bt zero visible

  for (int chunk = 0; chunk < 8; ++chunk) {
    const int c0 = chunk * 8;

    // ---- B loads: elem-coalesced, 9 consecutive lanes per contiguous 72-B run
    float2 wv[9];
#pragma unroll
    for (int p = 0; p < 9; ++p) {
      int e = tid + p * 256;
      int run = e / 9, el = e - run * 9;
      int cc = run >> 5, o = run & 31;
      wv[p] = *(const float2*)(wb + (c0 + cc) * 518400 + o * 8100 + el * 2);
    }
    // ---- A loads: per-lane 16-B x-run per fragment group (both b-rows)
    float2 ax[2][3][2][2];   // [mt][s][gi][half]
#pragma unroll
    for (int s = 0; s < 3; ++s)
#pragma unroll
      for (int gi = 0; gi < 2; ++gi) {
        int g = s * 8 + q * 2 + gi;
        int cc = g / 3, kh = g - cc * 3;
        long off = (long)(c0 + cc) * 1024 + kh * 32;
        const float2* p0 = (const float2*)(xb0 + off);
        const float2* p1 = (const float2*)(xb1 + off);
        ax[0][s][gi][0] = p0[0]; ax[0][s][gi][1] = p0[1];
        ax[1][s][gi][0] = p1[0]; ax[1][s][gi][1] = p1[1];
      }

    if (chunk) __syncthreads();   // previous chunk's MFMA readers done

    // ---- convert + write Bt (kw' 0..2 only)
#pragma unroll
    for (int p = 0; p < 9; ++p) {
      int e = tid + p * 256;
      int run = e / 9, el = e - run * 9;
      int cc = run >> 5, o = run & 31;
      int obase = o * 104 + cc * 12;
#pragma unroll
      for (int h = 0; h < 2; ++h) {
        int f = el * 2 + h;            // 0..17
        int jj = f / 9, r9 = f - jj * 9;
        int kh = r9 / 3, kw = r9 - kh * 3;
        Bt[jj * 3328 + obase + kh * 4 + kw] = f2bf(h ? wv[p].y : wv[p].x);
      }
    }
    __syncthreads();

    // ---- MFMA: 3 k-steps, A-frags straight from registers
#pragma unroll
    for (int s = 0; s < 3; ++s) {
      bf16x8 bfr[2][2];
#pragma unroll
      for (int jj = 0; jj < 2; ++jj)
#pragma unroll
        for (int nt = 0; nt < 2; ++nt)
          bfr[jj][nt] = *reinterpret_cast<const bf16x8*>(
              &Bt[jj * 3328 + (nt * 16 + lrow) * 104 + s * 32 + q * 8]);

#pragma unroll
      for (int mt = 0; mt < 2; ++mt) {
        unsigned short ha[2][4];
#pragma unroll
        for (int gi = 0; gi < 2; ++gi) {
          ha[gi][0] = f2bf(ax[mt][s][gi][0].x);
          ha[gi][1] = f2bf(ax[mt][s][gi][0].y);
          ha[gi][2] = f2bf(ax[mt][s][gi][1].x);
          ha[gi][3] = f2bf(ax[mt][s][gi][1].y);
        }
        union { unsigned short u[8]; bf16x8 v; } fa0, fa1;
#pragma unroll
        for (int gi = 0; gi < 2; ++gi) {
          fa0.u[gi * 4 + 0] = ha[gi][0];
          fa0.u[gi * 4 + 1] = ha[gi][1];
          fa0.u[gi * 4 + 2] = ha[gi][2];
          fa0.u[gi * 4 + 3] = ha[gi][3];      // slot3 pairs with B zero
          fa1.u[gi * 4 + 0] = ha[gi][1];
          fa1.u[gi * 4 + 1] = ha[gi][2];
          fa1.u[gi * 4 + 2] = ha[gi][3];
          fa1.u[gi * 4 + 3] = ha[gi][0];      // slot3 pairs with B zero
        }
#pragma unroll
        for (int nt = 0; nt < 2; ++nt) {
          acc[mt][0][nt] = __builtin_amdgcn_mfma_f32_16x16x32_bf16(fa0.v, bfr[0][nt], acc[mt][0][nt], 0, 0, 0);
          acc[mt][1][nt] = __builtin_amdgcn_mfma_f32_16x16x32_bf16(fa1.v, bfr[1][nt], acc[mt][1][nt], 0, 0, 0);
        }
      }
    }
  }

  // ---- epilogue: D[row=q*4+r][col=lrow]; row->b(16-slab), col->o; float2 over (ij0,ij0+1)
#pragma unroll
  for (int nt = 0; nt < 2; ++nt) {
    int o = oh * 32 + nt * 16 + lrow;
    float2 bv = *(const float2*)(bias + o * 900 + ij0);
#pragma unroll
    for (int mt = 0; mt < 2; ++mt) {
#pragma unroll
      for (int r = 0; r < 4; ++r) {
        int b = wave * 32 + mt * 16 + q * 4 + r;
        float2 res;
        res.x = acc[mt][0][nt][r] + bv.x;
        res.y = acc[mt][1][nt][r] + bv.y;
        *(float2*)(out + b * 57600 + o * 900 + ij0) = res;
      }
    }
  }
}

extern "C" void kernel_launch(void* const* d_in, const int* in_sizes, int n_in,
                              void* d_out, int out_size, void* d_ws, size_t ws_size,
                              hipStream_t stream) {
  const float* x    = (const float*)d_in[0];
  const float* wgt  = (const float*)d_in[1];
  const float* bias = (const float*)d_in[2];
  float* out        = (float*)d_out;
  lcl_kernel<<<dim3(900), dim3(256), 0, stream>>>(x, wgt, bias, out);
}